// Round 17
// baseline (84.833 us; speedup 1.0000x reference)
//
#include <hip/hip_runtime.h>

// FixedActionDecoder: sims = (X/||x||) @ (A/||a||cols); segment-max over
// ACTION_INDEX=[0,0,0,0,1,1,1,1,1,2,3]; argmax; one-hot.
// Row-norm of X is argmax-invariant -> skipped.
//
// r17 = final exploration: R=4 rows/lane with HALF-phases (untried combo;
// r7/r8's R=4 used line-splitting quarter-phases, r5/r10's low-occupancy
// failures were DMA-specific). Mechanism: r9's LDS pipe (22.5 CU-cyc/row)
// nearly co-limits with HBM (25.6); the fixed-per-tile W broadcast (176 of
// 240 LDS ops) amortized over 256 rows drops LDS to 14.25 cyc/row.
//  - 256-row wave tiles; half-phase staging = 32 instrs, each 8 FULL 128B
//    lines (r9's exact coalescing -> no over-fetch).
//  - 64-thread (1-wave) blocks, 39680 B LDS -> 4 blocks/CU = 4 waves/CU.
//    4-wave demand >> HBM supply -> HBM saturates despite 1 wave/SIMD.
//  - staging/compute/W-path instructions byte-equivalent to r9's.
// Sentinels: WRITE_SIZE>25MB = spill; dur>78.7us -> revert to r16 champion.
// Convicted (never retry): DMA staging (r5/r10), reg-staging arrays (r6),
// quarter-phases (r7/r8), fused prep (r7), fused repair (r11), steal
// atomics (r12), per-lane streaming (r14), same-iter reg prefetch (r15).
// Numerics: f32 pass + gap<TAU ballot -> f64 repair (absmax 0 all rounds).

#define NP 11
#define TAU 1e-3f
#define LROW 36  // LDS row stride (dwords): 32 data + 4 pad (verified 0-conflict)

__device__ __align__(16) float g_W32[704];      // [(d>>2)*44 + p*4 + (d&3)]
__device__ double g_W64[704];                   // [d*11 + p]
__device__ unsigned long long g_bits[1 << 20];  // near-tie flags, 1 bit/row

// Parallel prep (~2us): thread d owns row d of A; column norms via LDS.
__global__ void prep(const float* __restrict__ A) {
    __shared__ double sq[64][NP + 1];  // +1 pad
    __shared__ double sc[NP];
    const int d = threadIdx.x;  // 0..63
    double a[NP];
    #pragma unroll
    for (int p = 0; p < NP; ++p) {
        a[p] = (double)A[d * NP + p];
        sq[d][p] = a[p] * a[p];
    }
    __syncthreads();
    if (d < NP) {
        double ss = 0.0;
        #pragma unroll
        for (int r = 0; r < 64; ++r) ss += sq[r][d];
        sc[d] = 1.0 / fmax(sqrt(ss), 1e-8);
    }
    __syncthreads();
    #pragma unroll
    for (int p = 0; p < NP; ++p) {
        double w = a[p] * sc[p];
        g_W64[d * NP + p] = w;
        g_W32[(d >> 2) * 44 + p * 4 + (d & 3)] = (float)w;  // d-major quad
    }
}

__device__ __forceinline__ void argmax_gap(const float* s, int& idx, float& gap) {
    // Segment max per ACTION_INDEX = [0,0,0,0, 1,1,1,1,1, 2, 3]
    float m0 = fmaxf(fmaxf(s[0], s[1]), fmaxf(s[2], s[3]));
    float m1 = fmaxf(fmaxf(fmaxf(s[4], s[5]), s[6]), fmaxf(s[7], s[8]));
    float m2 = s[9], m3 = s[10];
    idx = 0; float best = m0;
    if (m1 > best) { best = m1; idx = 1; }
    if (m2 > best) { best = m2; idx = 2; }
    if (m3 > best) { best = m3; idx = 3; }
    float second = -3.4e38f;
    if (idx != 0) second = fmaxf(second, m0);
    if (idx != 1) second = fmaxf(second, m1);
    if (idx != 2) second = fmaxf(second, m2);
    if (idx != 3) second = fmaxf(second, m3);
    gap = best - second;
}

__global__ __launch_bounds__(64) void decode(const float* __restrict__ X,
                                             float* __restrict__ out, int B) {
    __shared__ float buf[256][LROW];  // 36864 B half-phase buffer (1 wave)
    __shared__ float w_lds[704];      // 2816 B; total 39680 -> 4 blk/CU

    const int lane = threadIdx.x;  // 64-thread block = one wave

    // Copy W into LDS: 176 float4s over 64 lanes.
    for (int t = lane; t < 176; t += 64)
        reinterpret_cast<float4*>(w_lds)[t] =
            reinterpret_cast<const float4*>(g_W32)[t];
    __syncthreads();  // single wave: cheap

    const float4* X4 = reinterpret_cast<const float4*>(X);
    const int gwave = blockIdx.x;
    const int nwaves = gridDim.x;

    #pragma unroll 1
    for (int base = gwave * 256; base < B; base += nwaves * 256) {
        float acc[4][NP];
        #pragma unroll
        for (int j = 0; j < 4; ++j)
            #pragma unroll
            for (int p = 0; p < NP; ++p) acc[j][p] = 0.0f;

        #pragma unroll
        for (int st = 0; st < 2; ++st) {  // d half: st*32 .. st*32+31
            // Stage 256 rows x 32 floats; instr i covers 8 FULL 128B lines
            // (8 lanes/row x 16 B contiguous) -- r9's exact pattern.
            #pragma unroll
            for (int i = 0; i < 32; ++i) {
                int fid = i * 64 + lane;  // 0..2047
                int row = fid >> 3;       // 0..255
                int f = fid & 7;          // 0..7
                int r = base + row;
                if (r >= B) r = B - 1;    // tail clamp (dup read, harmless)
                float4 v = X4[(size_t)r * 16 + st * 8 + f];
                *reinterpret_cast<float4*>(&buf[row][f * 4]) = v;
            }
            __builtin_amdgcn_wave_barrier();  // wave-private buf: fence only

            // Per 4-d chunk: 4 lane b128 (X rows) + 11 uniform b128 (W
            // quads) + 176 v_fma_f32. unroll 1: W never bulk-hoisted (r2).
            #pragma unroll 1
            for (int kk = 0; kk < 8; ++kk) {
                const float* wrow = &w_lds[(st * 8 + kk) * 44];
                float4 x0 = *reinterpret_cast<const float4*>(&buf[lane][kk * 4]);
                float4 x1 = *reinterpret_cast<const float4*>(&buf[lane + 64][kk * 4]);
                float4 x2 = *reinterpret_cast<const float4*>(&buf[lane + 128][kk * 4]);
                float4 x3 = *reinterpret_cast<const float4*>(&buf[lane + 192][kk * 4]);
                #pragma unroll
                for (int p = 0; p < NP; ++p) {
                    float4 wq = *reinterpret_cast<const float4*>(&wrow[p * 4]);
                    float u;
                    u = fmaf(x0.x, wq.x, acc[0][p]); u = fmaf(x0.y, wq.y, u);
                    u = fmaf(x0.z, wq.z, u);         acc[0][p] = fmaf(x0.w, wq.w, u);
                    u = fmaf(x1.x, wq.x, acc[1][p]); u = fmaf(x1.y, wq.y, u);
                    u = fmaf(x1.z, wq.z, u);         acc[1][p] = fmaf(x1.w, wq.w, u);
                    u = fmaf(x2.x, wq.x, acc[2][p]); u = fmaf(x2.y, wq.y, u);
                    u = fmaf(x2.z, wq.z, u);         acc[2][p] = fmaf(x2.w, wq.w, u);
                    u = fmaf(x3.x, wq.x, acc[3][p]); u = fmaf(x3.y, wq.y, u);
                    u = fmaf(x3.z, wq.z, u);         acc[3][p] = fmaf(x3.w, wq.w, u);
                }
            }
            __builtin_amdgcn_wave_barrier();
        }

        // Epilogue: per 64-row group, argmax + flag + coalesced store.
        #pragma unroll
        for (int j = 0; j < 4; ++j) {
            int idx; float gap;
            argmax_gap(acc[j], idx, gap);
            unsigned long long m = __ballot(gap < TAU);
            if (lane == 0) g_bits[(base >> 6) + j] = m;
            int r = base + j * 64 + lane;
            if (r < B) {
                float4 o;
                o.x = (idx == 0) ? 1.0f : 0.0f;
                o.y = (idx == 1) ? 1.0f : 0.0f;
                o.z = (idx == 2) ? 1.0f : 0.0f;
                o.w = (idx == 3) ? 1.0f : 0.0f;
                reinterpret_cast<float4*>(out)[r] = o;
            }
        }
    }
}

__global__ __launch_bounds__(256) void repair(const float* __restrict__ X,
                                              float* __restrict__ out, int B) {
    __shared__ double w64[704];  // copy of g_W64
    const int tid = threadIdx.x;
    for (int i = tid; i < 704; i += 256) w64[i] = g_W64[i];
    __syncthreads();

    const int nwords = (B + 63) >> 6;
    for (int t = blockIdx.x * blockDim.x + tid; t < nwords;
         t += gridDim.x * blockDim.x) {
        unsigned long long m = g_bits[t];
        while (m) {
            int b = __builtin_ctzll(m);
            m &= m - 1;
            int row = t * 64 + b;
            if (row >= B) continue;

            double s[NP];
            #pragma unroll
            for (int p = 0; p < NP; ++p) s[p] = 0.0;
            #pragma unroll 1
            for (int d = 0; d < 64; ++d) {
                double x = (double)X[(size_t)row * 64 + d];
                #pragma unroll
                for (int p = 0; p < NP; ++p)
                    s[p] = fma(x, w64[d * NP + p], s[p]);
            }

            double m0 = fmax(fmax(s[0], s[1]), fmax(s[2], s[3]));
            double m1 = fmax(fmax(fmax(s[4], s[5]), s[6]), fmax(s[7], s[8]));
            double m2 = s[9], m3 = s[10];
            int idx = 0; double best = m0;
            if (m1 > best) { best = m1; idx = 1; }
            if (m2 > best) { best = m2; idx = 2; }
            if (m3 > best) { best = m3; idx = 3; }

            float4 o;
            o.x = (idx == 0) ? 1.0f : 0.0f;
            o.y = (idx == 1) ? 1.0f : 0.0f;
            o.z = (idx == 2) ? 1.0f : 0.0f;
            o.w = (idx == 3) ? 1.0f : 0.0f;
            reinterpret_cast<float4*>(out)[row] = o;
        }
    }
}

extern "C" void kernel_launch(void* const* d_in, const int* in_sizes, int n_in,
                              void* d_out, int out_size, void* d_ws, size_t ws_size,
                              hipStream_t stream) {
    const float* X = (const float*)d_in[0];
    const float* A = (const float*)d_in[1];
    float* out = (float*)d_out;
    const int B = in_sizes[0] / 64;

    hipLaunchKernelGGL(prep, dim3(1), dim3(64), 0, stream, A);
    hipLaunchKernelGGL(decode, dim3(2048), dim3(64), 0, stream, X, out, B);
    hipLaunchKernelGGL(repair, dim3(128), dim3(256), 0, stream, X, out, B);
}